// Round 10
// baseline (315.561 us; speedup 1.0000x reference)
//
#include <hip/hip_runtime.h>
#include <hip/hip_bf16.h>
#include <stdint.h>

#define B_SZ 8192
#define D_SZ 1024
#define H_SZ 1024
#define O_SZ 512
#define E_SZ 8

typedef float f32x16 __attribute__((ext_vector_type(16)));
typedef __bf16 bf16x8 __attribute__((ext_vector_type(8)));

typedef __attribute__((address_space(1))) uint32_t gu32;
typedef __attribute__((address_space(3))) uint32_t lu32;

__device__ __forceinline__ unsigned short f2bf(float f) {
    union { __hip_bfloat16 h; unsigned short u; } c;
    c.h = __float2bfloat16(f);
    return c.u;
}
__device__ __forceinline__ float bf2f(unsigned short u) {
    union { float f; uint32_t u; } c;
    c.u = ((uint32_t)u) << 16;
    return c.f;
}

// Panel layout (for GEMM A and B operands): [panel=row>>8][kblk=k>>3][row&255][8 elems].
// A 32x32x16 MFMA fragment read from LDS in this layout is 32 lanes x 16 B contiguous
// (512 B = banks 0..31) -> ZERO bank conflicts, no swizzle; glds sources are contiguous.

// ------- fused: convert x -> panelized bf16 AND 20 gate logits + 3 softmaxes -------
// 1024 threads = 16 waves, one x-row per wave; panel write via LDS restage (coalesced).
__global__ __launch_bounds__(1024) void k_convert_gates(const float* __restrict__ x,
                                                        const float* __restrict__ Wg,
                                                        const float* __restrict__ Wgs,
                                                        unsigned short* __restrict__ x_kb,
                                                        float* __restrict__ g_all) {
    __shared__ unsigned short xs[16][D_SZ];   // 32 KiB
    const int wv = threadIdx.x >> 6;
    const int lane = threadIdx.x & 63;
    const int b0 = blockIdx.x * 16;
    const int b = b0 + wv;
    const float* xr = x + (size_t)b * D_SZ;
    float acc[20];
#pragma unroll
    for (int j = 0; j < 20; ++j) acc[j] = 0.f;
#pragma unroll 4
    for (int it = 0; it < 16; ++it) {
        const int d = it * 64 + lane;
        const float xv = xr[d];
        xs[wv][d] = f2bf(xv);
        const float* w0 = Wg + (size_t)d * 6;
        const float* w1 = Wg + (size_t)D_SZ * 6 + (size_t)d * 6;
        const float* ws = Wgs + (size_t)d * 8;
#pragma unroll
        for (int j = 0; j < 6; ++j) acc[j] += xv * w0[j];
#pragma unroll
        for (int j = 0; j < 6; ++j) acc[6 + j] += xv * w1[j];
#pragma unroll
        for (int j = 0; j < 8; ++j) acc[12 + j] += xv * ws[j];
    }
#pragma unroll
    for (int j = 0; j < 20; ++j) {
        float v = acc[j];
#pragma unroll
        for (int s = 32; s > 0; s >>= 1) v += __shfl_down(v, s, 64);
        acc[j] = v;
    }
    if (lane == 0) {
        float* g = g_all + (size_t)b * 20;
#pragma unroll
        for (int t = 0; t < 3; ++t) {
            int base = (t == 0) ? 0 : (t == 1 ? 6 : 12);
            int cnt  = (t == 2) ? 8 : 6;
            float m = -1e30f;
            for (int j = 0; j < cnt; ++j) m = fmaxf(m, acc[base + j]);
            float ex[8]; float sum = 0.f;
            for (int j = 0; j < cnt; ++j) { ex[j] = __expf(acc[base + j] - m); sum += ex[j]; }
            float inv = 1.f / sum;
            for (int j = 0; j < cnt; ++j) g[base + j] = ex[j] * inv;
        }
    }
    __syncthreads();
    // panel write: 2048 units (128 kblk x 16 rows), 2 per thread; coalesced 256 B runs.
    const char* lb = (const char*)&xs[0][0];
#pragma unroll
    for (int p = 0; p < 2; ++p) {
        const int u = p * 1024 + threadIdx.x;
        const int kblk = u >> 4, r16 = u & 15;
        int4 v = *(const int4*)(lb + r16 * 2048 + kblk * 16);
        *(int4*)(x_kb + (size_t)(b0 >> 8) * (D_SZ * 256) + (size_t)kblk * 2048
                 + ((b0 & 255) + r16) * 8) = v;
    }
}

// ------- transpose+convert+panelize: in [E][R][C] f32 -> out panel[C>>8][R/8][c&255][8] bf16 -------
__global__ __launch_bounds__(512) void k_transpose_panel(const float* __restrict__ in,
                                                         unsigned short* __restrict__ out,
                                                         int R, int C) {
    __shared__ float tile[64][65];
    const float* src = in + (size_t)blockIdx.z * R * C;
    unsigned short* dst = out + (size_t)blockIdx.z * R * C;
    int c0 = blockIdx.x * 64, r0 = blockIdx.y * 64;   // c: output-row dim, r: K dim
    int tx = threadIdx.x, ty = threadIdx.y;           // block (64,8)
#pragma unroll
    for (int rr = ty; rr < 64; rr += 8)
        tile[rr][tx] = src[(size_t)(r0 + rr) * C + c0 + tx];
    __syncthreads();
    // thread -> unit (kblk-local = ty, crow = tx): 8 f32 col-reads -> one 16B store
    union { ushort4 h[2]; int4 q; } u;
#pragma unroll
    for (int s = 0; s < 8; ++s)
        ((unsigned short*)&u)[s] = f2bf(tile[ty * 8 + s][tx]);
    const int c = c0 + tx;
    *(int4*)(dst + (size_t)(c >> 8) * (R * 256) + (size_t)((r0 >> 3) + ty) * 2048
             + (c & 255) * 8) = u.q;
}

// ------- 256x256 bf16 GEMM: 32x32x16 MFMA, panelized conflict-free LDS, ring-4 BK=32 -------
// C = relu(A * Bt^T + bias). 512 thr = 8 waves (2M x 4N); wave 128x64 = acc[4][2] f32x16.
// LDS 128 KiB = 4 ring buffers x 32 KiB { A [4kblk][256][16B], B same @+16KiB }.
// Pipeline = round-9 verified (reads one phase ahead; stage t+3 post-barrier; counted
// vmcnt(4), tails 0; RAW: vmcnt+barrier before next-tile reads; WAR: barrier precedes restage).
// Frag reads: 32 lanes x 16 B contiguous -> zero bank conflicts (no swizzle anywhere).
// 32x32 mappings verified in r6: A row=lane&31,k=(lane>>5)*8; C/D col=lane&31,
// row=(reg&3)+8*(reg>>2)+4*(lane>>5).
template <bool PANEL_OUT>
__global__ __launch_bounds__(512, 2) void k_gemm_p(
    const unsigned short* __restrict__ A,
    const unsigned short* __restrict__ Bt,
    const float* __restrict__ bias,
    unsigned short* __restrict__ C,
    int M, int N, int K,
    long long sA, long long sB, long long sBias, long long sC, int e_base) {

    const int tid = threadIdx.x;
    const int lane = tid & 63, wid = tid >> 6;
    const int wr = wid >> 2, wc = wid & 3;       // 2 x 4 wave grid
    const int lr32 = lane & 31, hi = lane >> 5;

    // bijective XCD swizzle on flat grid (nwg % 8 == 0 for all launches here)
    const int nwg = gridDim.x;
    const int wg = blockIdx.x;
    const int swz = (wg & 7) * (nwg >> 3) + (wg >> 3);
    const int nx = N >> 8;
    const int my = M >> 8;
    const int bx = swz % nx;
    const int t1 = swz / nx;
    const int by = t1 % my;
    const int e  = t1 / my + e_base;

    A    += (size_t)((long long)e * sA);
    Bt   += (size_t)((long long)e * sB);
    bias += (size_t)((long long)e * sBias);
    C    += (size_t)((long long)e * sC);

    const int m0 = by * 256, n0 = bx * 256;

    __shared__ __align__(16) unsigned short lds[65536];   // 128 KiB
    char* ldsb = (char*)lds;

    // staging: linear dest tid*16; panel source contiguous per wave (1 KB/instr)
    const int skb = tid >> 8;         // 0/1
    const int srw = tid & 255;

    auto stageA = [&](int tt) {
        const int bb = (tt & 3) * 32768;
        const unsigned short* s0 = A + (size_t)(m0 >> 8) * K * 256
                                     + (size_t)(tt * 4 + skb) * 2048 + srw * 8;
        __builtin_amdgcn_global_load_lds((gu32*)s0, (lu32*)(ldsb + bb + tid * 16), 16, 0, 0);
        __builtin_amdgcn_global_load_lds((gu32*)(s0 + 4096),
                                         (lu32*)(ldsb + bb + 8192 + tid * 16), 16, 0, 0);
    };
    auto stageB = [&](int tt) {
        const int bb = (tt & 3) * 32768 + 16384;
        const unsigned short* s0 = Bt + (size_t)(n0 >> 8) * K * 256
                                      + (size_t)(tt * 4 + skb) * 2048 + srw * 8;
        __builtin_amdgcn_global_load_lds((gu32*)s0, (lu32*)(ldsb + bb + tid * 16), 16, 0, 0);
        __builtin_amdgcn_global_load_lds((gu32*)(s0 + 4096),
                                         (lu32*)(ldsb + bb + 8192 + tid * 16), 16, 0, 0);
    };

    // fragment byte offsets: A frag (mi,s) @ bb + abase + mi*512 + s*8192 ; B (nj,s) likewise
    const int abase = (wr * 128 + lr32) * 16 + hi * 4096;
    const int bbase = 16384 + (wc * 64 + lr32) * 16 + hi * 4096;

    auto readA = [&](bf16x8* d, int bb, int mb) {
#pragma unroll
        for (int q = 0; q < 4; ++q) {
            const int mi = mb + (q >> 1), s = q & 1;
            d[q] = *(const bf16x8*)(ldsb + bb + abase + mi * 512 + s * 8192);
        }
    };
    auto readB = [&](bf16x8* d, int bb) {
#pragma unroll
        for (int q = 0; q < 4; ++q) {
            const int nj = q >> 1, s = q & 1;
            d[q] = *(const bf16x8*)(ldsb + bb + bbase + nj * 512 + s * 8192);
        }
    };

    f32x16 acc[4][2];
#pragma unroll
    for (int i = 0; i < 4; ++i)
#pragma unroll
        for (int j = 0; j < 2; ++j)
            acc[i][j] = (f32x16)(0.f);

    auto mfma8 = [&](const bf16x8* fa, const bf16x8* fb, int rb) {
        __builtin_amdgcn_s_setprio(1);
#pragma unroll
        for (int i = 0; i < 2; ++i)
#pragma unroll
            for (int j = 0; j < 2; ++j)
#pragma unroll
                for (int s = 0; s < 2; ++s)
                    acc[rb + i][j] = __builtin_amdgcn_mfma_f32_32x32x16_bf16(
                        fa[i * 2 + s], fb[j * 2 + s], acc[rb + i][j], 0, 0, 0);
        __builtin_amdgcn_s_setprio(0);
    };

    const int NT = K >> 5;   // 32 (even)

    // prologue: stage tiles 0,1,2 (12 glds); vmcnt(8) -> tile 0 landed; read tile-0 U+B
    stageA(0); stageB(0); stageA(1); stageB(1); stageA(2); stageB(2);
    asm volatile("s_waitcnt vmcnt(8)" ::: "memory");
    asm volatile("s_barrier" ::: "memory");

    bf16x8 aU0[4], aL0[4], b0[4], aU1[4], aL1[4], b1v[4];
    readA(aU0, 0, 0); readB(b0, 0);

    for (int t = 0; t < NT; t += 2) {
        const int bb0 = (t & 3) * 32768;
        const int bb1 = ((t + 1) & 3) * 32768;
        const int bb2 = ((t + 2) & 3) * 32768;

        // ---- phase (t,U): read L-frags(t); ensure t+1 landed; MFMA U(t) ----
        readA(aL0, bb0, 2);
        if (t + 2 < NT) { asm volatile("s_waitcnt vmcnt(4)" ::: "memory"); }
        else            { asm volatile("s_waitcnt vmcnt(0)" ::: "memory"); }
        asm volatile("s_barrier" ::: "memory");
        if (t + 3 < NT) stageA(t + 3);
        mfma8(aU0, b0, 0);

        // ---- phase (t,L): read U+B frags(t+1); MFMA L(t) ----
        readA(aU1, bb1, 0); readB(b1v, bb1);
        asm volatile("s_barrier" ::: "memory");
        if (t + 3 < NT) stageB(t + 3);
        mfma8(aL0, b0, 2);

        // ---- phase (t+1,U): read L-frags(t+1); ensure t+2 landed; MFMA U(t+1) ----
        readA(aL1, bb1, 2);
        if (t + 3 < NT) { asm volatile("s_waitcnt vmcnt(4)" ::: "memory"); }
        else            { asm volatile("s_waitcnt vmcnt(0)" ::: "memory"); }
        asm volatile("s_barrier" ::: "memory");
        if (t + 4 < NT) stageA(t + 4);
        mfma8(aU1, b1v, 0);

        // ---- phase (t+1,L): read U+B frags(t+2); MFMA L(t+1) ----
        if (t + 2 < NT) { readA(aU0, bb2, 0); readB(b0, bb2); }
        asm volatile("s_barrier" ::: "memory");
        if (t + 4 < NT) stageB(t + 4);
        mfma8(aL1, b1v, 4 - 2);   // rb = 2
    }

    // ---- epilogue ----
    __syncthreads();
    unsigned short* ct = (unsigned short*)ldsb;   // logical [256 rows][256 cols] bf16
#pragma unroll
    for (int nj = 0; nj < 2; ++nj) {
        const int nn = wc * 64 + nj * 32 + lr32;
        const float bv = bias[n0 + nn];
#pragma unroll
        for (int mi = 0; mi < 4; ++mi) {
#pragma unroll
            for (int r = 0; r < 16; ++r) {
                const int mloc = wr * 128 + mi * 32 + (r & 3) + 8 * (r >> 2) + 4 * hi;
                float v = fmaxf(acc[mi][nj][r] + bv, 0.f);
                if (PANEL_OUT) {
                    // store with XOR'd 16B-unit index so the panel readout is coalesced
                    const int pu = (nn >> 3) ^ (mloc & 7);
                    *(unsigned short*)(ldsb + mloc * 512 + pu * 16 + (nn & 7) * 2) = f2bf(v);
                } else {
                    ct[(size_t)mloc * 256 + nn] = f2bf(v);
                }
            }
        }
    }
    __syncthreads();
    if (PANEL_OUT) {
        // write C panelized: unit (blk = global 16B-unit in N, row); contiguous per 256 thr
#pragma unroll
        for (int it = 0; it < 16; ++it) {
            const int u = it * 512 + tid;
            const int blk = u >> 8, row = u & 255;
            int4 v = *(const int4*)(ldsb + row * 512 + ((blk ^ (row & 7)) * 16));
            *(int4*)(C + (size_t)(m0 >> 8) * N * 256 + (size_t)((n0 >> 3) + blk) * 2048
                     + row * 8) = v;
        }
    } else {
#pragma unroll
        for (int it = 0; it < 16; ++it) {
            const int row = it * 16 + (tid >> 5);
            const int colE = (tid & 31) * 8;
            *(int4*)(&C[(size_t)(m0 + row) * N + n0 + colE]) =
                *(const int4*)(ldsb + it * 8192 + (size_t)tid * 16);
        }
    }
}

// ---------------- combine: out[b][t][o], 4 o's per thread (eo row-major) ----------------
__global__ __launch_bounds__(256) void k_combine(const unsigned short* __restrict__ eo,
                                                 const float* __restrict__ g_all,
                                                 float* __restrict__ out) {
    int idx4 = blockIdx.x * 256 + threadIdx.x;    // over B*O/4
    int b = idx4 >> 7;                            // O/4 = 128
    int o4 = (idx4 & 127) * 4;
    const float* g = g_all + (size_t)b * 20;
    float v[E_SZ][4];
#pragma unroll
    for (int e = 0; e < E_SZ; ++e) {
        ushort4 u = *(const ushort4*)(eo + (size_t)e * B_SZ * O_SZ + (size_t)b * O_SZ + o4);
        v[e][0] = bf2f(u.x); v[e][1] = bf2f(u.y); v[e][2] = bf2f(u.z); v[e][3] = bf2f(u.w);
    }
    float4 r0, r1, r2;
    float* p0 = (float*)&r0; float* p1 = (float*)&r1; float* p2 = (float*)&r2;
#pragma unroll
    for (int c = 0; c < 4; ++c) {
        p0[c] = g[0] * v[0][c] + g[1] * v[1][c] + g[2] * v[4][c] + g[3] * v[5][c]
              + g[4] * v[6][c] + g[5] * v[7][c];
        p1[c] = g[6] * v[2][c] + g[7] * v[3][c] + g[8] * v[4][c] + g[9] * v[5][c]
              + g[10] * v[6][c] + g[11] * v[7][c];
        float s = 0.f;
#pragma unroll
        for (int e = 0; e < E_SZ; ++e) s += g[12 + e] * v[e][c];
        p2[c] = s;
    }
    size_t ob = (size_t)b * (3 * O_SZ) + o4;
    *(float4*)(out + ob) = r0;
    *(float4*)(out + ob + O_SZ) = r1;
    *(float4*)(out + ob + 2 * O_SZ) = r2;
}

extern "C" void kernel_launch(void* const* d_in, const int* in_sizes, int n_in,
                              void* d_out, int out_size, void* d_ws, size_t ws_size,
                              hipStream_t stream) {
    const float* x   = (const float*)d_in[0];
    const float* W1  = (const float*)d_in[1];
    const float* b1  = (const float*)d_in[2];
    const float* W2  = (const float*)d_in[3];
    const float* b2  = (const float*)d_in[4];
    const float* Wg  = (const float*)d_in[5];
    const float* Wgs = (const float*)d_in[6];
    float* out = (float*)d_out;

    char* ws = (char*)d_ws;
    const size_t SZ_XBF  = (size_t)B_SZ * D_SZ * 2;           // 16 MB (panelized)
    const size_t SZ_W1T  = (size_t)E_SZ * H_SZ * D_SZ * 2;    // 16 MB (panelized)
    const size_t SZ_W2T  = (size_t)E_SZ * O_SZ * H_SZ * 2;    // 8 MB  (panelized)
    const size_t SZ_EO   = (size_t)E_SZ * B_SZ * O_SZ * 2;    // 64 MB (row-major)
    const size_t SZ_G    = (size_t)B_SZ * 20 * 4;             // 640 KB
    const size_t SZ_HBIG = (size_t)E_SZ * B_SZ * H_SZ * 2;    // 128 MB (panelized)

    unsigned short* x_kb = (unsigned short*)ws;              ws += SZ_XBF;
    unsigned short* W1T  = (unsigned short*)ws;              ws += SZ_W1T;
    unsigned short* W2T  = (unsigned short*)ws;              ws += SZ_W2T;
    unsigned short* eo   = (unsigned short*)ws;              ws += SZ_EO;
    float* g_all         = (float*)ws;                       ws += SZ_G;
    unsigned short* h_buf = (unsigned short*)ws;

    const size_t fixed = SZ_XBF + SZ_W1T + SZ_W2T + SZ_EO + SZ_G;
    const bool big = ws_size >= fixed + SZ_HBIG;

    // 1) fused convert(panelize) + gates; panelizing weight transposes
    k_convert_gates<<<B_SZ / 16, 1024, 0, stream>>>(x, Wg, Wgs, x_kb, g_all);
    dim3 tb(64, 8);
    k_transpose_panel<<<dim3(H_SZ / 64, D_SZ / 64, E_SZ), tb, 0, stream>>>(W1, W1T, D_SZ, H_SZ);
    k_transpose_panel<<<dim3(O_SZ / 64, H_SZ / 64, E_SZ), tb, 0, stream>>>(W2, W2T, H_SZ, O_SZ);

    // 2) expert GEMMs (256x256 tiles; flat 1D grids, all % 8 == 0)
    if (big) {
        k_gemm_p<true><<<(H_SZ / 256) * (B_SZ / 256) * E_SZ, 512, 0, stream>>>(
            x_kb, W1T, b1, h_buf, B_SZ, H_SZ, D_SZ,
            0LL, (long long)H_SZ * D_SZ, (long long)H_SZ, (long long)B_SZ * H_SZ, 0);
        k_gemm_p<false><<<(O_SZ / 256) * (B_SZ / 256) * E_SZ, 512, 0, stream>>>(
            h_buf, W2T, b2, eo, B_SZ, O_SZ, H_SZ,
            (long long)B_SZ * H_SZ, (long long)O_SZ * H_SZ, (long long)O_SZ, (long long)B_SZ * O_SZ, 0);
    } else {
        for (int e = 0; e < E_SZ; ++e) {
            k_gemm_p<true><<<(H_SZ / 256) * (B_SZ / 256), 512, 0, stream>>>(
                x_kb, W1T, b1, h_buf, B_SZ, H_SZ, D_SZ,
                0LL, (long long)H_SZ * D_SZ, (long long)H_SZ, 0LL, e);
            k_gemm_p<false><<<(O_SZ / 256) * (B_SZ / 256), 512, 0, stream>>>(
                h_buf, W2T, b2, eo, B_SZ, O_SZ, H_SZ,
                0LL, (long long)O_SZ * H_SZ, (long long)O_SZ, (long long)B_SZ * O_SZ, e);
        }
    }

    // 3) combine
    k_combine<<<(B_SZ * O_SZ / 4) / 256, 256, 0, stream>>>(eo, g_all, out);
}